// Round 1
// baseline (10513.171 us; speedup 1.0000x reference)
//
#include <hip/hip_runtime.h>
#include <math.h>

// Problem dims
static constexpr int B = 128, R = 36, F = 2048, SDIM = 4096, D = 1024, A = 512;
static constexpr int E = 1024, V = 10000, L = 21, T = 20;
static constexpr int G4 = 4 * D;  // 4096 gate width

// ---------------------------------------------------------------------------
// Kernel 1: stable descending argsort of sizes + permutation-dependent tables
// ---------------------------------------------------------------------------
__global__ void k_order(const int* __restrict__ sizes, const int* __restrict__ seqs,
                        float* __restrict__ out_seq, float* __restrict__ out_declen,
                        float* __restrict__ out_order,
                        int* __restrict__ order, int* __restrict__ declen_i,
                        int* __restrict__ map_feats, int* __restrict__ map_emb)
{
    __shared__ int so[B];
    int i = threadIdx.x;  // 128 threads
    int sz = sizes[i];
    int rank = 0;
    for (int j = 0; j < B; ++j) {
        int sj = sizes[j];
        rank += (sj > sz) || (sj == sz && j < i);  // stable, descending
    }
    so[rank] = i;
    __syncthreads();
    int o = so[i];
    order[i] = o;
    int dl = sizes[o] - 1;
    declen_i[i] = dl;
    out_declen[i] = (float)dl;
    out_order[i] = (float)o;
    for (int l = 0; l < L; ++l) out_seq[i * L + l] = (float)seqs[o * L + l];
    for (int r = 0; r < R; ++r) map_feats[i * R + r] = o * R + r;
    for (int t = 0; t < T; ++t) map_emb[i * T + t] = seqs[o * L + t];
}

// ---------------------------------------------------------------------------
// featsAvg[b][f] = mean_r feats[order[b]][r][f]
// ---------------------------------------------------------------------------
__global__ void k_featsavg(const float* __restrict__ feats, const int* __restrict__ order,
                           float* __restrict__ out)
{
    int idx = blockIdx.x * blockDim.x + threadIdx.x;  // b*F + f
    int b = idx >> 11, f = idx & (F - 1);
    const float* p = feats + ((size_t)order[b] * R) * F + f;
    float s = 0.f;
#pragma unroll
    for (int r = 0; r < R; ++r) s += p[r * F];
    out[idx] = s * (1.0f / R);
}

// ---------------------------------------------------------------------------
// Generic fp32 GEMM: out[m,n] = sum over up to 3 pairs X_p[m,:] . W_p[n,:]
//   + bias[n] + A0[m,n] + A1[m,n]; optional mask epilogue (t < dec_len[m] ? v : 0)
// X rows may be gathered via map1 (pair 1 only). M must be a multiple of 64.
// ---------------------------------------------------------------------------
#define BM 64
#define BN 64
#define BKK 16

__global__ __launch_bounds__(256) void k_gemm(
    int M, int N,
    const float* __restrict__ X1, int ldx1, const int* __restrict__ map1,
    const float* __restrict__ W1, int ldw1, int K1,
    const float* __restrict__ X2, int ldx2, const float* __restrict__ W2, int ldw2, int K2,
    const float* __restrict__ X3, int ldx3, const float* __restrict__ W3, int ldw3, int K3,
    const float* __restrict__ bias,
    const float* __restrict__ A0, int lda0,
    const float* __restrict__ A1, int lda1,
    float* __restrict__ out, int ldo,
    const int* __restrict__ mask_dl, int mask_t)
{
    __shared__ float Xs[BKK][BM + 4];
    __shared__ float Ws[BKK][BN + 4];
    const int tid = threadIdx.x;
    const int tx = tid & 15, ty = tid >> 4;
    const int bn = blockIdx.x * BN, bm = blockIdx.y * BM;
    const int lrow = tid >> 2, lc4 = (tid & 3) * 4;

    float acc[4][4];
#pragma unroll
    for (int i = 0; i < 4; ++i)
#pragma unroll
        for (int j = 0; j < 4; ++j) acc[i][j] = 0.f;

    const int xm = bm + lrow;
    const int wn = bn + lrow;
    const int wn_c = (wn < N) ? wn : (N - 1);

    for (int pair = 0; pair < 3; ++pair) {
        const float* X; const float* W; int ldx, ldw, K; const int* map;
        if (pair == 0)      { X = X1; W = W1; ldx = ldx1; ldw = ldw1; K = K1; map = map1; }
        else if (pair == 1) { X = X2; W = W2; ldx = ldx2; ldw = ldw2; K = K2; map = nullptr; }
        else                { X = X3; W = W3; ldx = ldx3; ldw = ldw3; K = K3; map = nullptr; }
        if (!X) continue;
        const int xr = map ? map[xm] : xm;
        const float* xp = X + (size_t)xr * ldx + lc4;
        const float* wp = W + (size_t)wn_c * ldw + lc4;
        for (int k0 = 0; k0 < K; k0 += BKK) {
            float4 xv = *(const float4*)(xp + k0);
            float4 wv = *(const float4*)(wp + k0);
            __syncthreads();  // previous tile's compute done before overwrite
            Xs[lc4 + 0][lrow] = xv.x; Xs[lc4 + 1][lrow] = xv.y;
            Xs[lc4 + 2][lrow] = xv.z; Xs[lc4 + 3][lrow] = xv.w;
            Ws[lc4 + 0][lrow] = wv.x; Ws[lc4 + 1][lrow] = wv.y;
            Ws[lc4 + 2][lrow] = wv.z; Ws[lc4 + 3][lrow] = wv.w;
            __syncthreads();
#pragma unroll
            for (int kk = 0; kk < BKK; ++kk) {
                float4 a = *(const float4*)(&Xs[kk][ty * 4]);
                float4 bb = *(const float4*)(&Ws[kk][tx * 4]);
                float av[4] = {a.x, a.y, a.z, a.w};
                float bv[4] = {bb.x, bb.y, bb.z, bb.w};
#pragma unroll
                for (int i = 0; i < 4; ++i)
#pragma unroll
                    for (int j = 0; j < 4; ++j)
                        acc[i][j] = fmaf(av[i], bv[j], acc[i][j]);
            }
        }
    }

#pragma unroll
    for (int i = 0; i < 4; ++i) {
        int m = bm + ty * 4 + i;
#pragma unroll
        for (int j = 0; j < 4; ++j) {
            int n = bn + tx * 4 + j;
            if (n < N) {
                float v = acc[i][j];
                if (bias) v += bias[n];
                if (A0) v += A0[(size_t)m * lda0 + n];
                if (A1) v += A1[(size_t)m * lda1 + n];
                if (mask_dl) v = (mask_t < mask_dl[m]) ? v : 0.f;
                out[(size_t)m * ldo + n] = v;
            }
        }
    }
}

// ---------------------------------------------------------------------------
// LSTM cell pointwise: gates g[b][4D] (i,f,g,o), state c -> hn, cn
// ---------------------------------------------------------------------------
__global__ void k_lstm(const float* __restrict__ g, const float* __restrict__ c,
                       float* __restrict__ hn, float* __restrict__ cn)
{
    int idx = blockIdx.x * blockDim.x + threadIdx.x;  // b*D + j
    int b = idx >> 10, j = idx & (D - 1);
    const float* gb = g + (size_t)b * G4;
    float gi = gb[j], gf = gb[D + j], gg = gb[2 * D + j], go = gb[3 * D + j];
    float si = 1.f / (1.f + expf(-gi));
    float sf = 1.f / (1.f + expf(-gf));
    float so = 1.f / (1.f + expf(-go));
    float cv = sf * c[idx] + si * tanhf(gg);
    hn[idx] = so * tanhf(cv);
    cn[idx] = cv;
}

// ---------------------------------------------------------------------------
// Attention scores + softmax: w[b][0..36]
// ---------------------------------------------------------------------------
__global__ void k_att(const float* __restrict__ h1_att, const float* __restrict__ img_att,
                      const float* __restrict__ sal_att, const float* __restrict__ Wa,
                      const float* __restrict__ ba, float* __restrict__ w)
{
    int b = blockIdx.x;
    int tid = threadIdx.x;
    int wave = tid >> 6, lane = tid & 63;
    __shared__ float s[R + 1];
    __shared__ float h1s[A];
    h1s[tid] = h1_att[(size_t)b * A + tid];
    h1s[tid + 256] = h1_att[(size_t)b * A + tid + 256];
    __syncthreads();
    for (int r = wave; r < R + 1; r += 4) {
        const float* base = (r < R) ? (img_att + ((size_t)b * R + r) * A) : (sal_att + (size_t)b * A);
        float p = 0.f;
        for (int a = lane; a < A; a += 64) {
            float v = h1s[a] + base[a];
            p += fmaxf(v, 0.f) * Wa[a];
        }
#pragma unroll
        for (int off = 32; off; off >>= 1) p += __shfl_down(p, off);
        if (lane == 0) s[r] = p + ba[0];
    }
    __syncthreads();
    if (tid < 64) {
        float v = (tid < R + 1) ? s[tid] : -INFINITY;
        float mx = v;
#pragma unroll
        for (int off = 32; off; off >>= 1) mx = fmaxf(mx, __shfl_down(mx, off));
        mx = __shfl(mx, 0);
        float e = (tid < R + 1) ? expf(v - mx) : 0.f;
        float sum = e;
#pragma unroll
        for (int off = 32; off; off >>= 1) sum += __shfl_down(sum, off);
        sum = __shfl(sum, 0);
        if (tid < R + 1) w[b * (R + 1) + tid] = e / sum;
    }
}

// ---------------------------------------------------------------------------
// aw[b][f] = sum_r feats_p[b][r][f]*w[b][r] + sal_w[b][f]*w[b][36]
// ---------------------------------------------------------------------------
__global__ void k_aw(const float* __restrict__ feats, const int* __restrict__ order,
                     const float* __restrict__ w, const float* __restrict__ sal_w,
                     float* __restrict__ aw)
{
    int idx = blockIdx.x * blockDim.x + threadIdx.x;  // b*F + f
    int b = idx >> 11, f = idx & (F - 1);
    __shared__ float ws[R + 1];
    if (threadIdx.x < R + 1) ws[threadIdx.x] = w[b * (R + 1) + threadIdx.x];
    __syncthreads();
    const float* fb = feats + ((size_t)order[b] * R) * F + f;
    float s = sal_w[idx] * ws[R];
#pragma unroll
    for (int r = 0; r < R; ++r) s = fmaf(fb[r * F], ws[r], s);
    aw[idx] = s;
}

// ---------------------------------------------------------------------------
// Masked carry update
// ---------------------------------------------------------------------------
__global__ void k_update(const int* __restrict__ dl, int t,
                         const float* __restrict__ h1n, const float* __restrict__ c1n,
                         const float* __restrict__ h2n, const float* __restrict__ c2n,
                         float* __restrict__ h1, float* __restrict__ c1,
                         float* __restrict__ h2, float* __restrict__ c2)
{
    int idx = blockIdx.x * blockDim.x + threadIdx.x;  // b*D + j
    int b = idx >> 10;
    if (t < dl[b]) {
        h1[idx] = h1n[idx]; c1[idx] = c1n[idx];
        h2[idx] = h2n[idx]; c2[idx] = c2n[idx];
    }
}

// ---------------------------------------------------------------------------
static inline void gemm(hipStream_t s, int M, int N,
    const float* X1, int ldx1, const int* map1, const float* W1, int ldw1, int K1,
    const float* X2, int ldx2, const float* W2, int ldw2, int K2,
    const float* X3, int ldx3, const float* W3, int ldw3, int K3,
    const float* bias, const float* A0, int lda0, const float* A1, int lda1,
    float* out, int ldo, const int* mask_dl, int mask_t)
{
    dim3 grid((N + BN - 1) / BN, (M + BM - 1) / BM);
    k_gemm<<<grid, 256, 0, s>>>(M, N, X1, ldx1, map1, W1, ldw1, K1,
                                X2, ldx2, W2, ldw2, K2, X3, ldx3, W3, ldw3, K3,
                                bias, A0, lda0, A1, lda1, out, ldo, mask_dl, mask_t);
}

extern "C" void kernel_launch(void* const* d_in, const int* in_sizes, int n_in,
                              void* d_out, int out_size, void* d_ws, size_t ws_size,
                              hipStream_t stream)
{
    const float* feats    = (const float*)d_in[0];
    const float* salf     = (const float*)d_in[1];
    const int*   seqs     = (const int*)d_in[2];
    const int*   sizes    = (const int*)d_in[3];
    const float* emb      = (const float*)d_in[4];
    const float* td_wih   = (const float*)d_in[5];
    const float* td_whh   = (const float*)d_in[6];
    const float* td_b     = (const float*)d_in[7];
    const float* lang_wih = (const float*)d_in[8];
    const float* lang_whh = (const float*)d_in[9];
    const float* lang_b   = (const float*)d_in[10];
    const float* Waf      = (const float*)d_in[11];
    const float* baf      = (const float*)d_in[12];
    const float* Wad      = (const float*)d_in[13];
    const float* bad      = (const float*)d_in[14];
    const float* Wsal     = (const float*)d_in[15];
    const float* bsal     = (const float*)d_in[16];
    const float* Was      = (const float*)d_in[17];
    const float* bas      = (const float*)d_in[18];
    const float* Wa       = (const float*)d_in[19];
    const float* ba       = (const float*)d_in[20];
    const float* Wout     = (const float*)d_in[21];
    const float* bout     = (const float*)d_in[22];

    float* out_preds = (float*)d_out;
    float* out_seq   = out_preds + (size_t)B * T * V;
    float* out_dl    = out_seq + B * L;
    float* out_order = out_dl + B;

    char* wsb = (char*)d_ws;
    size_t off = 0;
    auto alloc = [&](size_t bytes) -> char* {
        char* p = wsb + off;
        off += (bytes + 255) & ~(size_t)255;
        return p;
    };
    int*   order     = (int*)alloc(B * 4);
    int*   declen_i  = (int*)alloc(B * 4);
    int*   map_feats = (int*)alloc(B * R * 4);
    int*   map_emb   = (int*)alloc(B * T * 4);
    float* featsAvg  = (float*)alloc((size_t)B * F * 4);
    float* img_att   = (float*)alloc((size_t)B * R * A * 4);
    float* sal_w     = (float*)alloc((size_t)B * F * 4);
    float* sal_att   = (float*)alloc((size_t)B * A * 4);
    float* const1    = (float*)alloc((size_t)B * G4 * 4);
    float* emb_pre   = (float*)alloc((size_t)B * T * G4 * 4);
    float* states    = (float*)alloc((size_t)4 * B * D * 4);  // h1,c1,h2,c2
    float* h1 = states, *c1 = states + B * D, *h2 = states + 2 * B * D, *c2 = states + 3 * B * D;
    float* h1n       = (float*)alloc((size_t)B * D * 4);
    float* c1n       = (float*)alloc((size_t)B * D * 4);
    float* h2n       = (float*)alloc((size_t)B * D * 4);
    float* c2n       = (float*)alloc((size_t)B * D * 4);
    float* g1        = (float*)alloc((size_t)B * G4 * 4);
    float* g2        = (float*)alloc((size_t)B * G4 * 4);
    float* h1_att    = (float*)alloc((size_t)B * A * 4);
    float* wbuf      = (float*)alloc((size_t)B * (R + 1) * 4);
    float* awbuf     = (float*)alloc((size_t)B * F * 4);

    // zero initial states
    hipMemsetAsync(states, 0, (size_t)4 * B * D * 4, stream);

    // sort + tables (+ writes seq/dec_len/order outputs)
    k_order<<<1, B, 0, stream>>>(sizes, seqs, out_seq, out_dl, out_order,
                                 order, declen_i, map_feats, map_emb);

    // featsAvg
    k_featsavg<<<(B * F) / 256, 256, 0, stream>>>(feats, order, featsAvg);

    // img_att[b*R+r][a] = feats_p . Waf^T + baf     (M=4608,N=512,K=2048)
    gemm(stream, B * R, A, feats, F, map_feats, Waf, F, F,
         nullptr, 0, nullptr, 0, 0, nullptr, 0, nullptr, 0, 0,
         baf, nullptr, 0, nullptr, 0, img_att, A, nullptr, 0);

    // sal_w = sal_p @ Wsal^T + bsal                 (M=128,N=2048,K=4096)
    gemm(stream, B, F, salf, SDIM, order, Wsal, SDIM, SDIM,
         nullptr, 0, nullptr, 0, 0, nullptr, 0, nullptr, 0, 0,
         bsal, nullptr, 0, nullptr, 0, sal_w, F, nullptr, 0);

    // sal_att = sal_w @ Was^T + bas                 (M=128,N=512,K=2048)
    gemm(stream, B, A, sal_w, F, nullptr, Was, F, F,
         nullptr, 0, nullptr, 0, 0, nullptr, 0, nullptr, 0, 0,
         bas, nullptr, 0, nullptr, 0, sal_att, A, nullptr, 0);

    // const1 = featsAvg @ td_wih[:,D:D+F]^T + td_b  (M=128,N=4096,K=2048)
    gemm(stream, B, G4, featsAvg, F, nullptr, td_wih + D, G4, F,
         nullptr, 0, nullptr, 0, 0, nullptr, 0, nullptr, 0, 0,
         td_b, nullptr, 0, nullptr, 0, const1, G4, nullptr, 0);

    // emb_pre[b*T+t] = emb[seq_p[b][t]] @ td_wih[:,D+F:]^T   (M=2560,N=4096,K=1024)
    gemm(stream, B * T, G4, emb, E, map_emb, td_wih + D + F, G4, E,
         nullptr, 0, nullptr, 0, 0, nullptr, 0, nullptr, 0, 0,
         nullptr, nullptr, 0, nullptr, 0, emb_pre, G4, nullptr, 0);

    for (int t = 0; t < T; ++t) {
        // g1 = h2 @ td_wih[:,0:D]^T + h1 @ td_whh^T + const1 + emb_pre[:,t,:]
        gemm(stream, B, G4, h2, D, nullptr, td_wih, G4, D,
             h1, D, td_whh, D, D, nullptr, 0, nullptr, 0, 0,
             nullptr, const1, G4, emb_pre + (size_t)t * G4, T * G4,
             g1, G4, nullptr, 0);
        k_lstm<<<(B * D) / 256, 256, 0, stream>>>(g1, c1, h1n, c1n);

        // h1_att = h1n @ Wad^T + bad
        gemm(stream, B, A, h1n, D, nullptr, Wad, D, D,
             nullptr, 0, nullptr, 0, 0, nullptr, 0, nullptr, 0, 0,
             bad, nullptr, 0, nullptr, 0, h1_att, A, nullptr, 0);

        k_att<<<B, 256, 0, stream>>>(h1_att, img_att, sal_att, Wa, ba, wbuf);
        k_aw<<<(B * F) / 256, 256, 0, stream>>>(feats, order, wbuf, sal_w, awbuf);

        // g2 = aw @ lang_wih[:,0:F]^T + h1n @ lang_wih[:,F:]^T + h2 @ lang_whh^T + lang_b
        gemm(stream, B, G4, awbuf, F, nullptr, lang_wih, F + D, F,
             h1n, D, lang_wih + F, F + D, D,
             h2, D, lang_whh, D, D,
             lang_b, nullptr, 0, nullptr, 0, g2, G4, nullptr, 0);
        k_lstm<<<(B * D) / 256, 256, 0, stream>>>(g2, c2, h2n, c2n);

        // logits -> preds[:, t, :] with mask epilogue
        gemm(stream, B, V, h2n, D, nullptr, Wout, D, D,
             nullptr, 0, nullptr, 0, 0, nullptr, 0, nullptr, 0, 0,
             bout, nullptr, 0, nullptr, 0, out_preds + (size_t)t * V, T * V,
             declen_i, t);

        k_update<<<(B * D) / 256, 256, 0, stream>>>(declen_i, t, h1n, c1n, h2n, c2n,
                                                    h1, c1, h2, c2);
    }
}

// Round 2
// 3747.236 us; speedup vs baseline: 2.8056x; 2.8056x over previous
//
#include <hip/hip_runtime.h>
#include <math.h>

typedef unsigned short ushort_t;
typedef unsigned int uint_t;

static constexpr int B = 128, R = 36, SDIM = 4096, F = 2048, D = 1024, A = 512;
static constexpr int E = 1024, V = 10000, L = 21, T = 20;

typedef short bf16x8 __attribute__((ext_vector_type(8)));
typedef float f32x4 __attribute__((ext_vector_type(4)));

__device__ __forceinline__ ushort_t f2b(float x) {
    uint_t u = __float_as_uint(x);
    return (ushort_t)((u + 0x7FFFu + ((u >> 16) & 1u)) >> 16);
}
__device__ __forceinline__ float b2f(ushort_t h) {
    return __uint_as_float(((uint_t)h) << 16);
}
__device__ __forceinline__ void cvt8(const float* __restrict__ s, ushort_t* __restrict__ d) {
    float4 a = *(const float4*)s;
    float4 b = *(const float4*)(s + 4);
    uint4 o;
    o.x = f2b(a.x) | ((uint_t)f2b(a.y) << 16);
    o.y = f2b(a.z) | ((uint_t)f2b(a.w) << 16);
    o.z = f2b(b.x) | ((uint_t)f2b(b.y) << 16);
    o.w = f2b(b.z) | ((uint_t)f2b(b.w) << 16);
    *(uint4*)d = o;
}

// ---------------------------------------------------------------------------
// order/sort + index tables + integer outputs (as floats)
// ---------------------------------------------------------------------------
__global__ void k_order(const int* __restrict__ sizes, const int* __restrict__ seqs,
                        float* __restrict__ out_seq, float* __restrict__ out_declen,
                        float* __restrict__ out_order,
                        int* __restrict__ order, int* __restrict__ declen_i,
                        int* __restrict__ map_emb2)
{
    __shared__ int so[B];
    int i = threadIdx.x;
    int sz = sizes[i];
    int rank = 0;
    for (int j = 0; j < B; ++j) {
        int sj = sizes[j];
        rank += (sj > sz) || (sj == sz && j < i);
    }
    so[rank] = i;
    __syncthreads();
    int o = so[i];
    order[i] = o;
    int dl = sizes[o] - 1;
    declen_i[i] = dl;
    out_declen[i] = (float)dl;
    out_order[i] = (float)o;
    for (int l = 0; l < L; ++l) out_seq[i * L + l] = (float)seqs[o * L + l];
    for (int t = 0; t < T; ++t) map_emb2[t * B + i] = seqs[o * L + t];
}

// ---------------------------------------------------------------------------
// bulk fp32 -> bf16 conversion (9 weight segments)
// ---------------------------------------------------------------------------
struct CvtArgs { const float* s[9]; ushort_t* d[9]; };

__global__ __launch_bounds__(256) void k_cvt(CvtArgs a)
{
    const int cum1 = 2097152, cum2 = 2621440, cum3 = 4194304, cum4 = 4718592,
              cum5 = 4849664, cum6 = 4915200, cum7 = 5963776, cum8 = 6094848,
              tot  = 7374848;
    for (int c = blockIdx.x * blockDim.x + threadIdx.x; c < tot; c += gridDim.x * blockDim.x) {
        int seg = (c >= cum1) + (c >= cum2) + (c >= cum3) + (c >= cum4) +
                  (c >= cum5) + (c >= cum6) + (c >= cum7) + (c >= cum8);
        int base;
        switch (seg) {
            case 0: base = 0; break;      case 1: base = cum1; break;
            case 2: base = cum2; break;   case 3: base = cum3; break;
            case 4: base = cum4; break;   case 5: base = cum5; break;
            case 6: base = cum6; break;   case 7: base = cum7; break;
            default: base = cum8; break;
        }
        size_t local = (size_t)(c - base) * 8;
        cvt8(a.s[seg] + local, a.d[seg] + local);
    }
}

__global__ __launch_bounds__(256) void k_cvt1(const float* __restrict__ s, ushort_t* __restrict__ d, int nchunks)
{
    for (int c = blockIdx.x * blockDim.x + threadIdx.x; c < nchunks; c += gridDim.x * blockDim.x)
        cvt8(s + (size_t)c * 8, d + (size_t)c * 8);
}

// gather+convert feats -> feats_pb [B][R][F] bf16, via order
__global__ __launch_bounds__(256) void k_gather_feats(const float* __restrict__ feats,
                                                      const int* __restrict__ order,
                                                      ushort_t* __restrict__ dst)
{
    const int tot = B * R * F / 8;      // 1179648
    const int perb = R * F / 8;         // 9216
    for (int c = blockIdx.x * blockDim.x + threadIdx.x; c < tot; c += gridDim.x * blockDim.x) {
        int b = c / perb, rem = c - b * perb;
        size_t so = (size_t)order[b] * (R * F) + (size_t)rem * 8;
        size_t dofs = (size_t)b * (R * F) + (size_t)rem * 8;
        cvt8(feats + so, dst + dofs);
    }
}

__global__ __launch_bounds__(256) void k_gather_sal(const float* __restrict__ sal,
                                                    const int* __restrict__ order,
                                                    ushort_t* __restrict__ dst)
{
    const int tot = B * SDIM / 8;  // 65536
    for (int c = blockIdx.x * blockDim.x + threadIdx.x; c < tot; c += gridDim.x * blockDim.x) {
        int b = c >> 9, rem = c & 511;
        cvt8(sal + (size_t)order[b] * SDIM + rem * 8, dst + (size_t)b * SDIM + rem * 8);
    }
}

// featsAvg_b[b][f] = mean_r feats[order[b]][r][f]  (bf16 out)
__global__ __launch_bounds__(256) void k_featsavg(const float* __restrict__ feats,
                                                  const int* __restrict__ order,
                                                  ushort_t* __restrict__ out)
{
    int b = blockIdx.x;
    int f0 = threadIdx.x * 8;
    const float* p = feats + (size_t)order[b] * (R * F) + f0;
    float s[8];
#pragma unroll
    for (int j = 0; j < 8; ++j) s[j] = 0.f;
    for (int r = 0; r < R; ++r) {
        float4 a = *(const float4*)(p + (size_t)r * F);
        float4 c = *(const float4*)(p + (size_t)r * F + 4);
        s[0] += a.x; s[1] += a.y; s[2] += a.z; s[3] += a.w;
        s[4] += c.x; s[5] += c.y; s[6] += c.z; s[7] += c.w;
    }
    uint4 o;
    o.x = f2b(s[0] * (1.f / R)) | ((uint_t)f2b(s[1] * (1.f / R)) << 16);
    o.y = f2b(s[2] * (1.f / R)) | ((uint_t)f2b(s[3] * (1.f / R)) << 16);
    o.z = f2b(s[4] * (1.f / R)) | ((uint_t)f2b(s[5] * (1.f / R)) << 16);
    o.w = f2b(s[6] * (1.f / R)) | ((uint_t)f2b(s[7] * (1.f / R)) << 16);
    *(uint4*)(out + (size_t)b * F + f0) = o;
}

// ---------------------------------------------------------------------------
// big GEMM: BM=256, BN=64, 4 waves (each 128m x 32n).  out = X@W^T (+bias)
// mode 0: f32 out; mode 1: bf16 out; mode 2: masked transposed store (logits)
// ---------------------------------------------------------------------------
__global__ __launch_bounds__(256) void k_gemm_big(
    const ushort_t* __restrict__ X, int ldx, const int* __restrict__ map,
    const ushort_t* __restrict__ W, int ldw, int K, int N,
    const float* __restrict__ bias,
    float* __restrict__ outf, ushort_t* __restrict__ outb, int ldo,
    const int* __restrict__ mask_dl, int mode)
{
    int tid = threadIdx.x;
    int w = tid >> 6, l = tid & 63;
    int lm = l & 15, lk = l >> 4;
    int m0 = blockIdx.x * 256 + (w >> 1) * 128;
    int n0 = blockIdx.y * 64 + (w & 1) * 32;

    const ushort_t* ap[8];
#pragma unroll
    for (int i = 0; i < 8; ++i) {
        int m = m0 + i * 16 + lm;
        int row = map ? map[m] : m;
        ap[i] = X + (size_t)row * ldx + lk * 8;
    }
    const ushort_t* bp[2];
#pragma unroll
    for (int j = 0; j < 2; ++j) {
        int n = n0 + j * 16 + lm;
        if (n >= N) n = N - 1;
        bp[j] = W + (size_t)n * ldw + lk * 8;
    }

    f32x4 acc[8][2];
#pragma unroll
    for (int i = 0; i < 8; ++i)
#pragma unroll
        for (int j = 0; j < 2; ++j) acc[i][j] = (f32x4)0.f;

    for (int k = 0; k < K; k += 32) {
        bf16x8 bv[2], av[8];
#pragma unroll
        for (int j = 0; j < 2; ++j) bv[j] = *(const bf16x8*)(bp[j] + k);
#pragma unroll
        for (int i = 0; i < 8; ++i) av[i] = *(const bf16x8*)(ap[i] + k);
#pragma unroll
        for (int i = 0; i < 8; ++i)
#pragma unroll
            for (int j = 0; j < 2; ++j)
                acc[i][j] = __builtin_amdgcn_mfma_f32_16x16x32_bf16(av[i], bv[j], acc[i][j], 0, 0, 0);
    }

    int r0 = lk * 4;
#pragma unroll
    for (int i = 0; i < 8; ++i) {
#pragma unroll
        for (int j = 0; j < 2; ++j) {
            int n = n0 + j * 16 + lm;
            if (n < N) {
                float bv = bias ? bias[n] : 0.f;
#pragma unroll
                for (int r = 0; r < 4; ++r) {
                    int m = m0 + i * 16 + r0 + r;
                    float v = acc[i][j][r] + bv;
                    if (mode == 0) outf[(size_t)m * ldo + n] = v;
                    else if (mode == 1) outb[(size_t)m * ldo + n] = f2b(v);
                    else {
                        int b_ = m & 127, t_ = m >> 7;
                        outf[((size_t)b_ * T + t_) * ldo + n] = (t_ < mask_dl[b_]) ? v : 0.f;
                    }
                }
            }
        }
    }
}

// ---------------------------------------------------------------------------
// small GEMM: BM=32, BN=32, 4 waves (each one 16x16 tile)
// ---------------------------------------------------------------------------
__global__ __launch_bounds__(256) void k_gemm_small(
    const ushort_t* __restrict__ X, int ldx,
    const ushort_t* __restrict__ W, int ldw, int K,
    const float* __restrict__ bias,
    float* __restrict__ outf, ushort_t* __restrict__ outb, int ldo)
{
    int tid = threadIdx.x;
    int w = tid >> 6, l = tid & 63;
    int lm = l & 15, lk = l >> 4;
    int m0 = blockIdx.x * 32 + (w >> 1) * 16;
    int n0 = blockIdx.y * 32 + (w & 1) * 16;

    const ushort_t* ap = X + (size_t)(m0 + lm) * ldx + lk * 8;
    const ushort_t* bp = W + (size_t)(n0 + lm) * ldw + lk * 8;
    f32x4 acc = (f32x4)0.f;
    for (int k = 0; k < K; k += 32) {
        bf16x8 a = *(const bf16x8*)(ap + k);
        bf16x8 b = *(const bf16x8*)(bp + k);
        acc = __builtin_amdgcn_mfma_f32_16x16x32_bf16(a, b, acc, 0, 0, 0);
    }
    int n = n0 + lm;
    float bv = bias ? bias[n] : 0.f;
#pragma unroll
    for (int r = 0; r < 4; ++r) {
        int m = m0 + lk * 4 + r;
        float v = acc[r] + bv;
        outf[(size_t)m * ldo + n] = v;
        if (outb) outb[(size_t)m * ldo + n] = f2b(v);
    }
}

// ---------------------------------------------------------------------------
// fused gate GEMM + LSTM epilogue.
// Block: 64 rows x 16 gate-cols x 4 gates.  Wave = 16 rows, all 4 gates.
// C-fragment lanes hold i,f,g,o for identical (m,j) -> LSTM fully in-lane.
// ---------------------------------------------------------------------------
__device__ __forceinline__ void gates_pair(const ushort_t* __restrict__ X, int ldx,
                                           const ushort_t* __restrict__ W, int ldw, int K,
                                           int mrow, int j0, int lm, int lk, f32x4 acc[4])
{
    const ushort_t* ap = X + (size_t)(mrow + lm) * ldx + lk * 8;
    const ushort_t* bp[4];
#pragma unroll
    for (int g = 0; g < 4; ++g)
        bp[g] = W + (size_t)(g * 1024 + j0 + lm) * ldw + lk * 8;
    for (int k = 0; k < K; k += 32) {
        bf16x8 a = *(const bf16x8*)(ap + k);
        bf16x8 b0 = *(const bf16x8*)(bp[0] + k);
        bf16x8 b1 = *(const bf16x8*)(bp[1] + k);
        bf16x8 b2 = *(const bf16x8*)(bp[2] + k);
        bf16x8 b3 = *(const bf16x8*)(bp[3] + k);
        acc[0] = __builtin_amdgcn_mfma_f32_16x16x32_bf16(a, b0, acc[0], 0, 0, 0);
        acc[1] = __builtin_amdgcn_mfma_f32_16x16x32_bf16(a, b1, acc[1], 0, 0, 0);
        acc[2] = __builtin_amdgcn_mfma_f32_16x16x32_bf16(a, b2, acc[2], 0, 0, 0);
        acc[3] = __builtin_amdgcn_mfma_f32_16x16x32_bf16(a, b3, acc[3], 0, 0, 0);
    }
}

__global__ __launch_bounds__(256) void k_gates(
    const ushort_t* __restrict__ X1, int ldx1, const ushort_t* __restrict__ W1, int ldw1, int K1,
    const ushort_t* __restrict__ X2, int ldx2, const ushort_t* __restrict__ W2, int ldw2, int K2,
    const ushort_t* __restrict__ X3, int ldx3, const ushort_t* __restrict__ W3, int ldw3, int K3,
    const float* __restrict__ add1,        // const1 [B][4096] f32 (or null)
    const ushort_t* __restrict__ add2b,    // emb_pre [T*B][4096] bf16 (or null)
    const float* __restrict__ bias,        // lang_b [4096] (or null)
    float* __restrict__ cstate,            // [B][D] f32, in-place masked
    const ushort_t* __restrict__ hold,     // old h state bf16 [B][D]
    ushort_t* __restrict__ hnew,           // new h state bf16 [B][D]
    ushort_t* __restrict__ hn_out,         // unmasked h_n bf16 (or null)
    ushort_t* __restrict__ h2all,          // [T*B][D] bf16 (or null)
    const int* __restrict__ dl, int t)
{
    int tid = threadIdx.x;
    int w = tid >> 6, l = tid & 63;
    int lm = l & 15, lk = l >> 4;
    int mrow = blockIdx.x * 64 + w * 16;
    int j0 = blockIdx.y * 16;

    f32x4 acc[4];
#pragma unroll
    for (int g = 0; g < 4; ++g) acc[g] = (f32x4)0.f;

    gates_pair(X1, ldx1, W1, ldw1, K1, mrow, j0, lm, lk, acc);
    gates_pair(X2, ldx2, W2, ldw2, K2, mrow, j0, lm, lk, acc);
    if (X3) gates_pair(X3, ldx3, W3, ldw3, K3, mrow, j0, lm, lk, acc);

    int j = j0 + lm;
#pragma unroll
    for (int r = 0; r < 4; ++r) {
        int b_ = mrow + lk * 4 + r;
        float gi = acc[0][r], gf = acc[1][r], gg = acc[2][r], go = acc[3][r];
        if (add1) {
            size_t base = ((size_t)b_ << 12) + j;
            size_t ebase = (((size_t)t * B + b_) << 12) + j;
            gi += add1[base] + b2f(add2b[ebase]);
            gf += add1[base + 1024] + b2f(add2b[ebase + 1024]);
            gg += add1[base + 2048] + b2f(add2b[ebase + 2048]);
            go += add1[base + 3072] + b2f(add2b[ebase + 3072]);
        }
        if (bias) {
            gi += bias[j]; gf += bias[1024 + j]; gg += bias[2048 + j]; go += bias[3072 + j];
        }
        float si = 1.f / (1.f + expf(-gi));
        float sf = 1.f / (1.f + expf(-gf));
        float so = 1.f / (1.f + expf(-go));
        int sidx = b_ * 1024 + j;
        float cv = sf * cstate[sidx] + si * tanhf(gg);
        float h = so * tanhf(cv);
        ushort_t hb = f2b(h);
        bool act = t < dl[b_];
        if (act) { cstate[sidx] = cv; hnew[sidx] = hb; }
        else     { hnew[sidx] = hold[sidx]; }
        if (hn_out) hn_out[sidx] = hb;
        if (h2all) h2all[((size_t)t * B + b_) * 1024 + j] = hb;
    }
}

// ---------------------------------------------------------------------------
// fused attention scores + softmax + context (aw).  One block per batch row.
// ---------------------------------------------------------------------------
__global__ __launch_bounds__(256) void k_att_aw(
    const float* __restrict__ h1_att, const float* __restrict__ img_att,
    const float* __restrict__ sal_att, const float* __restrict__ Wa,
    const float* __restrict__ ba, const float* __restrict__ sal_w,
    const ushort_t* __restrict__ feats_pb, ushort_t* __restrict__ awb)
{
    int b = blockIdx.x;
    int tid = threadIdx.x;
    int w = tid >> 6, l = tid & 63;
    __shared__ float h1s[A], was[A], sc[R + 1], wsm[R + 1];
    h1s[tid] = h1_att[(size_t)b * A + tid];
    h1s[tid + 256] = h1_att[(size_t)b * A + tid + 256];
    was[tid] = Wa[tid];
    was[tid + 256] = Wa[tid + 256];
    __syncthreads();
    for (int r = w; r < R + 1; r += 4) {
        const float* base = (r < R) ? (img_att + ((size_t)b * R + r) * A) : (sal_att + (size_t)b * A);
        float p = 0.f;
        for (int a = l; a < A; a += 64) {
            float v = h1s[a] + base[a];
            p += fmaxf(v, 0.f) * was[a];
        }
#pragma unroll
        for (int off = 32; off; off >>= 1) p += __shfl_down(p, off);
        if (l == 0) sc[r] = p + ba[0];
    }
    __syncthreads();
    if (tid < 64) {
        float v = (tid < R + 1) ? sc[tid] : -INFINITY;
        float mx = v;
#pragma unroll
        for (int off = 32; off; off >>= 1) mx = fmaxf(mx, __shfl_down(mx, off));
        mx = __shfl(mx, 0);
        float e = (tid < R + 1) ? expf(v - mx) : 0.f;
        float sum = e;
#pragma unroll
        for (int off = 32; off; off >>= 1) sum += __shfl_down(sum, off);
        sum = __shfl(sum, 0);
        if (tid < R + 1) wsm[tid] = e / sum;
    }
    __syncthreads();
    // phase 2: aw for 8 contiguous f per thread
    int f0 = tid * 8;
    float s[8];
    float wsal = wsm[R];
    {
        float4 a = *(const float4*)(sal_w + (size_t)b * F + f0);
        float4 c = *(const float4*)(sal_w + (size_t)b * F + f0 + 4);
        s[0] = a.x * wsal; s[1] = a.y * wsal; s[2] = a.z * wsal; s[3] = a.w * wsal;
        s[4] = c.x * wsal; s[5] = c.y * wsal; s[6] = c.z * wsal; s[7] = c.w * wsal;
    }
    const ushort_t* fb = feats_pb + (size_t)b * (R * F) + f0;
#pragma unroll 4
    for (int r = 0; r < R; ++r) {
        uint4 pk = *(const uint4*)(fb + (size_t)r * F);
        float wr = wsm[r];
        const uint_t u[4] = {pk.x, pk.y, pk.z, pk.w};
#pragma unroll
        for (int q = 0; q < 4; ++q) {
            s[2 * q]     += b2f((ushort_t)(u[q] & 0xFFFF)) * wr;
            s[2 * q + 1] += b2f((ushort_t)(u[q] >> 16)) * wr;
        }
    }
    uint4 o;
    o.x = f2b(s[0]) | ((uint_t)f2b(s[1]) << 16);
    o.y = f2b(s[2]) | ((uint_t)f2b(s[3]) << 16);
    o.z = f2b(s[4]) | ((uint_t)f2b(s[5]) << 16);
    o.w = f2b(s[6]) | ((uint_t)f2b(s[7]) << 16);
    *(uint4*)(awb + (size_t)b * F + f0) = o;
}

// ---------------------------------------------------------------------------
extern "C" void kernel_launch(void* const* d_in, const int* in_sizes, int n_in,
                              void* d_out, int out_size, void* d_ws, size_t ws_size,
                              hipStream_t stream)
{
    const float* feats    = (const float*)d_in[0];
    const float* salf     = (const float*)d_in[1];
    const int*   seqs     = (const int*)d_in[2];
    const int*   sizes    = (const int*)d_in[3];
    const float* emb      = (const float*)d_in[4];
    const float* td_wih   = (const float*)d_in[5];
    const float* td_whh   = (const float*)d_in[6];
    const float* td_b     = (const float*)d_in[7];
    const float* lang_wih = (const float*)d_in[8];
    const float* lang_whh = (const float*)d_in[9];
    const float* lang_b   = (const float*)d_in[10];
    const float* Waf      = (const float*)d_in[11];
    const float* baf      = (const float*)d_in[12];
    const float* Wad      = (const float*)d_in[13];
    const float* bad      = (const float*)d_in[14];
    const float* Wsal     = (const float*)d_in[15];
    const float* bsal     = (const float*)d_in[16];
    const float* Was      = (const float*)d_in[17];
    const float* bas      = (const float*)d_in[18];
    const float* Wa       = (const float*)d_in[19];
    const float* ba       = (const float*)d_in[20];
    const float* Wout     = (const float*)d_in[21];
    const float* bout     = (const float*)d_in[22];

    float* out_preds = (float*)d_out;
    float* out_seq   = out_preds + (size_t)B * T * V;
    float* out_dl    = out_seq + B * L;
    float* out_order = out_dl + B;

    // scratch inside d_out (fully overwritten by the final logits GEMM)
    ushort_t* emb_pre_b = (ushort_t*)d_out;                              // 2560*4096 bf16 = 21 MB
    float* img_att = (float*)((char*)d_out + (size_t)22 * 1024 * 1024);  // 4608*512 f32 = 9.4 MB

    char* wsb = (char*)d_ws;
    size_t off = 0;
    auto alloc = [&](size_t bytes) -> char* {
        char* p = wsb + off;
        off += (bytes + 255) & ~(size_t)255;
        return p;
    };
    ushort_t* td_wih_b   = (ushort_t*)alloc((size_t)16777216 * 2);
    ushort_t* td_whh_b   = (ushort_t*)alloc((size_t)4194304 * 2);
    ushort_t* lang_wih_b = (ushort_t*)alloc((size_t)12582912 * 2);
    ushort_t* lang_whh_b = (ushort_t*)alloc((size_t)4194304 * 2);
    ushort_t* Waf_b      = (ushort_t*)alloc((size_t)1048576 * 2);
    ushort_t* Wad_b      = (ushort_t*)alloc((size_t)524288 * 2);
    ushort_t* Wsal_b     = (ushort_t*)alloc((size_t)8388608 * 2);
    ushort_t* Was_b      = (ushort_t*)alloc((size_t)1048576 * 2);
    ushort_t* embWout_b  = (ushort_t*)alloc((size_t)10240000 * 2);  // emb, then reused for Wout
    ushort_t* feats_pb   = (ushort_t*)alloc((size_t)B * R * F * 2);
    ushort_t* salf_pb    = (ushort_t*)alloc((size_t)B * SDIM * 2);
    ushort_t* featsAvg_b = (ushort_t*)alloc((size_t)B * F * 2);
    float*    sal_w      = (float*)alloc((size_t)B * F * 4);
    ushort_t* sal_wb     = (ushort_t*)alloc((size_t)B * F * 2);
    float*    sal_att    = (float*)alloc((size_t)B * A * 4);
    float*    const1     = (float*)alloc((size_t)B * 4096 * 4);
    ushort_t* h2all_b    = (ushort_t*)alloc((size_t)T * B * D * 2);
    float*    h1_att     = (float*)alloc((size_t)B * A * 4);
    ushort_t* awb        = (ushort_t*)alloc((size_t)B * F * 2);
    int* order    = (int*)alloc(B * 4);
    int* declen_i = (int*)alloc(B * 4);
    int* map_emb2 = (int*)alloc(T * B * 4);
    char* states_begin = wsb + off;
    float*    c1   = (float*)alloc((size_t)B * D * 4);
    float*    c2   = (float*)alloc((size_t)B * D * 4);
    ushort_t* h1b0 = (ushort_t*)alloc((size_t)B * D * 2);
    ushort_t* h1b1 = (ushort_t*)alloc((size_t)B * D * 2);
    ushort_t* h2b0 = (ushort_t*)alloc((size_t)B * D * 2);
    ushort_t* h2b1 = (ushort_t*)alloc((size_t)B * D * 2);
    ushort_t* h1n_b = (ushort_t*)alloc((size_t)B * D * 2);
    char* states_end = wsb + off;

    hipMemsetAsync(states_begin, 0, (size_t)(states_end - states_begin), stream);

    k_order<<<1, B, 0, stream>>>(sizes, seqs, out_seq, out_dl, out_order,
                                 order, declen_i, map_emb2);

    CvtArgs ca;
    ca.s[0] = td_wih;   ca.d[0] = td_wih_b;
    ca.s[1] = td_whh;   ca.d[1] = td_whh_b;
    ca.s[2] = lang_wih; ca.d[2] = lang_wih_b;
    ca.s[3] = lang_whh; ca.d[3] = lang_whh_b;
    ca.s[4] = Waf;      ca.d[4] = Waf_b;
    ca.s[5] = Wad;      ca.d[5] = Wad_b;
    ca.s[6] = Wsal;     ca.d[6] = Wsal_b;
    ca.s[7] = Was;      ca.d[7] = Was_b;
    ca.s[8] = emb;      ca.d[8] = embWout_b;
    k_cvt<<<2048, 256, 0, stream>>>(ca);

    k_gather_feats<<<2048, 256, 0, stream>>>(feats, order, feats_pb);
    k_gather_sal<<<256, 256, 0, stream>>>(salf, order, salf_pb);
    k_featsavg<<<B, 256, 0, stream>>>(feats, order, featsAvg_b);

    // img_att = feats_p @ Waf^T + baf   [4608 x 512]
    k_gemm_big<<<dim3(18, 8), 256, 0, stream>>>(feats_pb, F, nullptr, Waf_b, F, F, A,
                                                baf, img_att, nullptr, A, nullptr, 0);
    // sal_w = sal_p @ Wsal^T + bsal     [128 x 2048] (+bf16 mirror)
    k_gemm_small<<<dim3(4, 64), 256, 0, stream>>>(salf_pb, SDIM, Wsal_b, SDIM, SDIM,
                                                  bsal, sal_w, sal_wb, F);
    // sal_att = sal_w @ Was^T + bas     [128 x 512]
    k_gemm_small<<<dim3(4, 16), 256, 0, stream>>>(sal_wb, F, Was_b, F, F,
                                                  bas, sal_att, nullptr, A);
    // const1 = featsAvg @ td_wih[:,D:D+F]^T + td_b   [128 x 4096]
    k_gemm_small<<<dim3(4, 128), 256, 0, stream>>>(featsAvg_b, F, td_wih_b + 1024, 4096, F,
                                                   td_b, const1, nullptr, 4096);
    // emb_pre = emb[tok] @ td_wih[:,D+F:]^T   [2560 x 4096] bf16 out
    k_gemm_big<<<dim3(10, 64), 256, 0, stream>>>(embWout_b, E, map_emb2, td_wih_b + 3072, 4096, E, 4096,
                                                 nullptr, nullptr, emb_pre_b, 4096, nullptr, 1);

    for (int t = 0; t < T; ++t) {
        ushort_t* h1c = (t & 1) ? h1b1 : h1b0;
        ushort_t* h1n_state = (t & 1) ? h1b0 : h1b1;
        ushort_t* h2c = (t & 1) ? h2b1 : h2b0;
        ushort_t* h2n_state = (t & 1) ? h2b0 : h2b1;

        // gates1 + LSTM1: x1 = [h2, featsAvg(const1), emb_t(emb_pre)]
        k_gates<<<dim3(2, 64), 256, 0, stream>>>(
            h2c, D, td_wih_b, 4096, D,
            h1c, D, td_whh_b, D, D,
            nullptr, 0, nullptr, 0, 0,
            const1, emb_pre_b, nullptr,
            c1, h1c, h1n_state, h1n_b, nullptr, declen_i, t);

        // h1_att = h1n @ Wad^T + bad
        k_gemm_small<<<dim3(4, 16), 256, 0, stream>>>(h1n_b, D, Wad_b, D, D,
                                                      bad, h1_att, nullptr, A);

        k_att_aw<<<B, 256, 0, stream>>>(h1_att, img_att, sal_att, Wa, ba, sal_w,
                                        feats_pb, awb);

        // gates2 + LSTM2: x2 = [aw, h1n], rec h2
        k_gates<<<dim3(2, 64), 256, 0, stream>>>(
            awb, F, lang_wih_b, 3072, F,
            h1n_b, D, lang_wih_b + 2048, 3072, D,
            h2c, D, lang_whh_b, D, D,
            nullptr, nullptr, lang_b,
            c2, h2c, h2n_state, nullptr, h2all_b, declen_i, t);
    }

    // convert Wout (reuses emb's bf16 buffer) then one big masked logits GEMM
    k_cvt1<<<2048, 256, 0, stream>>>(Wout, embWout_b, 1280000);
    k_gemm_big<<<dim3(10, 157), 256, 0, stream>>>(h2all_b, D, nullptr, embWout_b, D, D, V,
                                                  bout, out_preds, nullptr, V, declen_i, 2);
}